// Round 3
// baseline (385.599 us; speedup 1.0000x reference)
//
#include <hip/hip_runtime.h>

// Heston Euler-Maruyama: 100000 paths x 512 steps, fp32.
// One wave (64 threads) per 64 paths, BARRIER-FREE wave-synchronous pipeline:
//   - block == 1 wave, so cross-lane LDS staging needs no s_barrier (DS pipe
//     is in-order per wave); no vmcnt(0)/lgkmcnt(0) drains anywhere.
//   - depth-2 register prefetch of z (named fA/fB buffers, no runtime index)
//   - stores are fire-and-forget; loads get >1 chunk of flight time.

#define N_PATHS 100000
#define N_STEPS 512
#define TROW    1539              // (N_STEPS+1)*3 floats per output path
#define CSTEP   16
#define NCHUNK  (N_STEPS / CSTEP) // 32
#define PB      64                // paths per block = one wave
#define ZSTR    34                // zl row stride (floats)
#define OSTR    49                // ol row stride (floats)

typedef float f32x4 __attribute__((ext_vector_type(4)));

__global__ __launch_bounds__(PB)
void heston_kernel(const float* __restrict__ z, float* __restrict__ out) {
    __shared__ float zl[PB * ZSTR];   // 8.7 KB, single-buffered (in-order DS pipe)
    __shared__ float ol[PB * OSTR];   // 12.5 KB

    const int tid = threadIdx.x;
    const int p0  = blockIdx.x * PB;
    const int lim = N_PATHS - p0;
    const bool ragged = (lim < PB);

    const float DTc   = 0.004f;
    const float THETA = 0.04f;
    const float SIGMA = 0.2f;
    const float RHO   = -0.7f;
    const float S0c   = 100.0f;
    const float V0c   = 0.04f;
    const float sqdt  = 0.06324555320f;                   // sqrt(DT)
    const float csdt  = 0.71414284285f * 0.06324555320f;  // sqrt(1-rho^2)*sqrt(DT)
    const float TAU0  = 2.048f;                           // N_STEPS*DT
    const float EDT   = expf(DTc);
    const float E0    = expf(-TAU0);

    // coalesced-load byte offsets (path-clamped: no OOB reads)
    int voff[8];
    #pragma unroll
    for (int j = 0; j < 8; ++j) {
        int pj = p0 + (tid >> 3) + 8 * j;
        if (pj > N_PATHS - 1) pj = N_PATHS - 1;
        voff[j] = pj * 4096 + (tid & 7) * 16;
    }
    const char* zb = (const char*)z;

    // prologue: chunk0 -> fA, chunk1 -> fB
    f32x4 fA[8], fB[8];
    #pragma unroll
    for (int j = 0; j < 8; ++j) fA[j] = *(const f32x4*)(zb + voff[j]);
    #pragma unroll
    for (int j = 0; j < 8; ++j) fB[j] = *(const f32x4*)(zb + voff[j] + 128);

    // t = 0 header
    {
        const float vs0 = fmaf(V0c, DTc, fmaf(THETA, TAU0, (V0c - THETA) * (1.0f - E0)));
        #pragma unroll
        for (int k = 0; k < 3; ++k) {
            int idx = k * PB + tid;
            int pl = idx / 3, si = idx - pl * 3;
            if (pl < lim)
                out[(size_t)(p0 + pl) * TROW + si] = (si == 0) ? S0c : (si == 1) ? V0c : vs0;
        }
    }

    // hoisted store offsets (pattern period 3 in k since 64 = 48+16)
    int gof[3], lof[3];
    {
        int pl = (tid >= 48) ? 1 : 0;
        int si = tid - pl * 48;
        #pragma unroll
        for (int j = 0; j < 3; ++j) {
            gof[j] = pl * TROW + si;
            lof[j] = pl * OSTR + si;
            pl += 1; si += 16;
            if (si >= 48) { si -= 48; pl += 1; }
        }
    }

    // zl <- fA (chunk 0)
    #pragma unroll
    for (int j = 0; j < 8; ++j) {
        float2* d = (float2*)&zl[((tid >> 3) + 8 * j) * ZSTR + (tid & 7) * 4];
        d[0] = make_float2(fA[j].x, fA[j].y);
        d[1] = make_float2(fA[j].z, fA[j].w);
    }

    float s = S0c, v = V0c, acc = V0c, tau = TAU0, e = E0;

    // fn: buffer to prefetch chunk c+2 into; fw: holds chunk c+1, written to zl
    auto chunk = [&](int c, f32x4 (&fn)[8], f32x4 (&fw)[8]) {
        if (c + 2 < NCHUNK) {
            const int cn = (c + 2) * 128;
            #pragma unroll
            for (int j = 0; j < 8; ++j) fn[j] = *(const f32x4*)(zb + voff[j] + cn);
        }

        // 16 Euler steps from zl -> ol
        #pragma unroll
        for (int dt = 0; dt < CSTEP; ++dt) {
            const float2 zz = *(const float2*)&zl[tid * ZSTR + 2 * dt];
            const float vp  = fmaxf(v, 0.0f);
            const float sv  = __builtin_amdgcn_sqrtf(vp);
            const float dW1 = sqdt * zz.x;
            const float dW2 = fmaf(RHO, dW1, csdt * zz.y);
            s = fmaf(s * sv, dW1, s);
            v = fmaxf(fmaf(SIGMA * sv, dW2, fmaf(THETA - vp, DTc, v)), 0.0f);
            acc += v;
            tau -= DTc;
            e *= EDT;
            const float vs = fmaf(acc, DTc, fmaf(THETA, tau, (v - THETA) * (1.0f - e)));
            ol[tid * OSTR + 3 * dt    ] = s;
            ol[tid * OSTR + 3 * dt + 1] = v;
            ol[tid * OSTR + 3 * dt + 2] = vs;
        }

        // coalesced store: 64 paths x 48 dwords, fire-and-forget
        if (!ragged) {
            float* oc = out + (size_t)p0 * TROW + 3 + 48 * c;
            #pragma unroll
            for (int g = 0; g < 16; ++g) {
                #pragma unroll
                for (int j = 0; j < 3; ++j) {
                    oc[gof[j] + g * (4 * TROW)] = ol[lof[j] + g * (4 * OSTR)];
                }
            }
        } else {
            for (int k = 0; k < 48; ++k) {
                int idx = k * PB + tid;
                int pl2 = idx / 48, si2 = idx - pl2 * 48;
                if (pl2 < lim)
                    out[(size_t)(p0 + pl2) * TROW + 3 + 48 * c + si2] = ol[pl2 * OSTR + si2];
            }
        }

        // zl <- fw (chunk c+1); its loads have had >= 1 full chunk of flight
        #pragma unroll
        for (int j = 0; j < 8; ++j) {
            float2* d = (float2*)&zl[((tid >> 3) + 8 * j) * ZSTR + (tid & 7) * 4];
            d[0] = make_float2(fw[j].x, fw[j].y);
            d[1] = make_float2(fw[j].z, fw[j].w);
        }
    };

    for (int cc = 0; cc < NCHUNK; cc += 2) {
        chunk(cc,     fA, fB);
        chunk(cc + 1, fB, fA);
    }
}

extern "C" void kernel_launch(void* const* d_in, const int* in_sizes, int n_in,
                              void* d_out, int out_size, void* d_ws, size_t ws_size,
                              hipStream_t stream) {
    const float* z = (const float*)d_in[0];
    float* out = (float*)d_out;
    const int nblocks = (N_PATHS + PB - 1) / PB;   // 1563
    heston_kernel<<<nblocks, PB, 0, stream>>>(z, out);
}